// Round 1
// baseline (46.820 us; speedup 1.0000x reference)
//
#include <hip/hip_runtime.h>
#include <math.h>

#define TT 16
#define HH 48
#define WW 48
#define CC 64
#define DD 6
#define VS (TT*HH*WW)   // 36864
#define SS (HH*WW)      // 2304
#define QT 8            // queries per block in attention kernel
#define NCH 8           // V-chunks
#define LC (VS/NCH)     // 4608 voxels per chunk

// ---------------- Kernel A: fused projection + LayerNorm ----------------
// Produces packed K records: KA[v]=(k0,k1,k2,k3), KB[v]=(k4,k5, t-7.5, h-23.5)
// and Q: Qp[s*8 + d] = q_d  (stride 8 for alignment).
__global__ __launch_bounds__(256) void proj_kernel(
    const float* __restrict__ vol, const float* __restrict__ slc,
    const float* __restrict__ w2d, const float* __restrict__ b2d,
    const float* __restrict__ g2d, const float* __restrict__ be2d,
    const float* __restrict__ w3d, const float* __restrict__ b3d,
    const float* __restrict__ g3d, const float* __restrict__ be3d,
    float4* __restrict__ KA, float4* __restrict__ KB, float* __restrict__ Qp)
{
    int gid = blockIdx.x * 256 + threadIdx.x;
    const float *src, *wgt, *bia, *gam, *bet;
    int pos, stride;
    bool isK = gid < VS;
    if (isK)                 { src = vol; wgt = w3d; bia = b3d; gam = g3d; bet = be3d; pos = gid;      stride = VS; }
    else if (gid < VS + SS)  { src = slc; wgt = w2d; bia = b2d; gam = g2d; bet = be2d; pos = gid - VS; stride = SS; }
    else return;

    float acc[DD] = {0.f,0.f,0.f,0.f,0.f,0.f};
    for (int c = 0; c < CC; ++c) {
        float x = src[c * stride + pos];
        #pragma unroll
        for (int d = 0; d < DD; ++d) acc[d] = fmaf(wgt[d*CC + c], x, acc[d]);
    }
    float mu = 0.f;
    #pragma unroll
    for (int d = 0; d < DD; ++d) { acc[d] += bia[d]; mu += acc[d]; }
    mu *= (1.f/DD);
    float var = 0.f;
    #pragma unroll
    for (int d = 0; d < DD; ++d) { float t = acc[d] - mu; var = fmaf(t, t, var); }
    var *= (1.f/DD);
    float inv = rsqrtf(var + 1e-5f);
    float y[DD];
    #pragma unroll
    for (int d = 0; d < DD; ++d) y[d] = (acc[d] - mu) * inv * gam[d] + bet[d];

    if (isK) {
        int v = pos;
        int t = v / (HH*WW);
        int r = v - t*(HH*WW);
        int h = r / WW;
        KA[v] = make_float4(y[0], y[1], y[2], y[3]);
        KB[v] = make_float4(y[4], y[5], (float)t - 7.5f, (float)h - 23.5f);
    } else {
        #pragma unroll
        for (int d = 0; d < DD; ++d) Qp[pos*8 + d] = y[d];
    }
}

// ---------------- Kernel B: attention partial sums ----------------
// Block = (query-tile qt of 8 queries) x (V-chunk cid of 4608 voxels).
// Raw exp (no max subtraction): |logit| <= 6 since LN output norm ~ sqrt(6).
// Accumulate (sum_p, sum_p*ct, sum_p*ch, sum_p*cw) per query.
__global__ __launch_bounds__(256) void attn_kernel(
    const float4* __restrict__ KA, const float4* __restrict__ KB,
    const float* __restrict__ Qp, float4* __restrict__ P4)
{
    int qt  = blockIdx.x / NCH;
    int cid = blockIdx.x - qt * NCH;
    int tid = threadIdx.x;

    float q[QT][DD];
    #pragma unroll
    for (int i = 0; i < QT; ++i)
        #pragma unroll
        for (int d = 0; d < DD; ++d)
            q[i][d] = Qp[(qt*QT + i)*8 + d];

    float sum[QT], c0[QT], c1[QT], c2[QT];
    #pragma unroll
    for (int i = 0; i < QT; ++i) { sum[i] = 0.f; c0[i] = 0.f; c1[i] = 0.f; c2[i] = 0.f; }

    int vbase = cid * LC;
    for (int j = tid; j < LC; j += 256) {
        int v = vbase + j;
        float4 a = KA[v];
        float4 b = KB[v];
        int wv = v - (v / WW) * WW;
        float cw = (float)wv - 23.5f;
        #pragma unroll
        for (int i = 0; i < QT; ++i) {
            float l = q[i][0] * a.x;
            l = fmaf(q[i][1], a.y, l);
            l = fmaf(q[i][2], a.z, l);
            l = fmaf(q[i][3], a.w, l);
            l = fmaf(q[i][4], b.x, l);
            l = fmaf(q[i][5], b.y, l);
            float p = __expf(l);
            sum[i] += p;
            c0[i] = fmaf(p, b.z, c0[i]);
            c1[i] = fmaf(p, b.w, c1[i]);
            c2[i] = fmaf(p, cw,  c2[i]);
        }
    }

    // butterfly reduce across the wave (plain sums — no max tracking needed)
    #pragma unroll
    for (int off = 32; off >= 1; off >>= 1) {
        #pragma unroll
        for (int i = 0; i < QT; ++i) {
            sum[i] += __shfl_xor(sum[i], off);
            c0[i]  += __shfl_xor(c0[i],  off);
            c1[i]  += __shfl_xor(c1[i],  off);
            c2[i]  += __shfl_xor(c2[i],  off);
        }
    }

    __shared__ float red[4][QT][4];
    int wave = tid >> 6, lane = tid & 63;
    if (lane == 0) {
        #pragma unroll
        for (int i = 0; i < QT; ++i) {
            red[wave][i][0] = sum[i];
            red[wave][i][1] = c0[i];
            red[wave][i][2] = c1[i];
            red[wave][i][3] = c2[i];
        }
    }
    __syncthreads();
    if (tid < QT) {
        int i = tid;
        float s  = red[0][i][0] + red[1][i][0] + red[2][i][0] + red[3][i][0];
        float a0 = red[0][i][1] + red[1][i][1] + red[2][i][1] + red[3][i][1];
        float a1 = red[0][i][2] + red[1][i][2] + red[2][i][2] + red[3][i][2];
        float a2 = red[0][i][3] + red[1][i][3] + red[2][i][3] + red[3][i][3];
        P4[cid*SS + qt*QT + i] = make_float4(s, a0, a1, a2);
    }
}

// ---------------- Kernel C: merge chunk partials, finalize flow ----------------
__global__ __launch_bounds__(256) void final_kernel(
    const float4* __restrict__ P4, float* __restrict__ out)
{
    int s = blockIdx.x * 256 + threadIdx.x;
    if (s >= SS) return;
    float sum = 0.f, c0 = 0.f, c1 = 0.f, c2 = 0.f;
    #pragma unroll
    for (int cid = 0; cid < NCH; ++cid) {
        float4 p = P4[cid*SS + s];
        sum += p.x; c0 += p.y; c1 += p.z; c2 += p.w;
    }
    float inv = 1.f / sum;
    int h = s / WW;
    int w = s - h * WW;
    out[s]          = c0 * inv;                              // t-channel (g_slice t = 0)
    out[SS + s]     = c1 * inv - ((float)h - 23.5f);         // h-channel
    out[2*SS + s]   = c2 * inv - ((float)w - 23.5f);         // w-channel
}

extern "C" void kernel_launch(void* const* d_in, const int* in_sizes, int n_in,
                              void* d_out, int out_size, void* d_ws, size_t ws_size,
                              hipStream_t stream)
{
    const float* vol  = (const float*)d_in[0];
    const float* slc  = (const float*)d_in[1];
    const float* w2d  = (const float*)d_in[2];
    const float* b2d  = (const float*)d_in[3];
    const float* g2d  = (const float*)d_in[4];
    const float* be2d = (const float*)d_in[5];
    const float* w3d  = (const float*)d_in[6];
    const float* b3d  = (const float*)d_in[7];
    const float* g3d  = (const float*)d_in[8];
    const float* be3d = (const float*)d_in[9];
    float* out = (float*)d_out;

    // workspace layout (1.48 MB total)
    float4* KA = (float4*)d_ws;            // VS float4
    float4* KB = KA + VS;                  // VS float4
    float*  Qp = (float*)(KB + VS);        // SS*8 floats
    float4* P4 = (float4*)(Qp + SS*8);     // NCH*SS float4

    proj_kernel<<<(VS + SS)/256, 256, 0, stream>>>(vol, slc, w2d, b2d, g2d, be2d,
                                                   w3d, b3d, g3d, be3d, KA, KB, Qp);
    attn_kernel<<<(SS/QT)*NCH, 256, 0, stream>>>(KA, KB, Qp, P4);
    final_kernel<<<(SS + 255)/256, 256, 0, stream>>>(P4, out);
}

// Round 3
// 30.623 us; speedup vs baseline: 1.5289x; 1.5289x over previous
//
#include <hip/hip_runtime.h>
#include <math.h>

#define TT 16
#define HH 48
#define WW 48
#define CC 64
#define DD 6
#define VS (TT*HH*WW)     // 36864 voxels
#define SS (HH*WW)        // 2304 queries
#define NT (VS/16)        // 2304 voxel-tiles of 16
#define QG 64             // queries per attn block (4 waves x 16)
#define NQG (SS/QG)       // 36 query groups
#define NCH 32            // voxel chunks
#define TPC (NT/NCH)      // 72 tiles per chunk
#define LOG2E 1.44269504088896f

typedef float  f4 __attribute__((ext_vector_type(4)));
typedef float  f2 __attribute__((ext_vector_type(2)));
typedef _Float16 h4 __attribute__((ext_vector_type(4)));
typedef _Float16 h2 __attribute__((ext_vector_type(2)));

// ---------------- Kernel A: projection + LN + fragment packing ----------------
// Blocks 0..143: voxels (K). Compute LN'd 6-dim K, then pack per 16-voxel tile
// the exact MFMA fragment layout:
//   lane L = r + 16g  (r=L&15, g=L>>4)
//   K half4 (A-frag of MFMA1): features g*4+j of voxel r      (0 beyond f=5)
//   G half4 (B-frag of MFMA2): coord c=r of voxels g*4+j      (c: ct,ch,cw,1)
// stored as one float4 per lane: [K halfs | G halfs].
// Blocks 144..152: queries (Q). LN, pre-scaled by log2(e), slots 6,7 = 0.
__global__ __launch_bounds__(256) void proj_kernel(
    const float* __restrict__ vol, const float* __restrict__ slc,
    const float* __restrict__ w2d, const float* __restrict__ b2d,
    const float* __restrict__ g2d, const float* __restrict__ be2d,
    const float* __restrict__ w3d, const float* __restrict__ b3d,
    const float* __restrict__ g3d, const float* __restrict__ be3d,
    f4* __restrict__ Kf, float* __restrict__ Qp)
{
    int tid = threadIdx.x;
    int gid = blockIdx.x * 256 + tid;
    __shared__ float sk[256][7];   // pad to 7: 2-way bank alias only (free)

    bool isK = gid < VS;
    const float *src, *wgt, *bia, *gam, *bet;
    int pos, stride;
    if (isK) { src = vol; wgt = w3d; bia = b3d; gam = g3d; bet = be3d; pos = gid;      stride = VS; }
    else     { src = slc; wgt = w2d; bia = b2d; gam = g2d; bet = be2d; pos = gid - VS; stride = SS; }

    float y[DD];
    {
        float acc[DD] = {0.f,0.f,0.f,0.f,0.f,0.f};
        for (int c = 0; c < CC; ++c) {
            float x = src[c * stride + pos];
            #pragma unroll
            for (int d = 0; d < DD; ++d) acc[d] = fmaf(wgt[d*CC + c], x, acc[d]);
        }
        float mu = 0.f;
        #pragma unroll
        for (int d = 0; d < DD; ++d) { acc[d] += bia[d]; mu += acc[d]; }
        mu *= (1.f/DD);
        float var = 0.f;
        #pragma unroll
        for (int d = 0; d < DD; ++d) { float t = acc[d] - mu; var = fmaf(t, t, var); }
        var *= (1.f/DD);
        float inv = rsqrtf(var + 1e-5f);
        #pragma unroll
        for (int d = 0; d < DD; ++d) y[d] = (acc[d] - mu) * inv * gam[d] + bet[d];
    }

    if (isK) {
        #pragma unroll
        for (int d = 0; d < DD; ++d) sk[tid][d] = y[d];
        __syncthreads();

        int tl = tid >> 4;              // tile within block (16 tiles)
        int r  = tid & 15;
        int tileg = blockIdx.x * 16 + tl;
        #pragma unroll
        for (int g = 0; g < 4; ++g) {
            h4 kh = (h4){0,0,0,0};
            if (g == 0) {
                kh = (h4){ (_Float16)sk[tl*16+r][0], (_Float16)sk[tl*16+r][1],
                           (_Float16)sk[tl*16+r][2], (_Float16)sk[tl*16+r][3] };
            } else if (g == 1) {
                kh = (h4){ (_Float16)sk[tl*16+r][4], (_Float16)sk[tl*16+r][5],
                           (_Float16)0.f, (_Float16)0.f };
            }
            h4 gh = (h4){0,0,0,0};
            if (r < 4) {
                #pragma unroll
                for (int j = 0; j < 4; ++j) {
                    int v   = tileg*16 + g*4 + j;
                    int t   = v / (HH*WW);
                    int rem = v - t*(HH*WW);
                    int h   = rem / WW;
                    int w   = rem - h*WW;
                    float val = (r==0) ? (float)t - 7.5f
                              : (r==1) ? (float)h - 23.5f
                              : (r==2) ? (float)w - 23.5f
                              :          1.0f;
                    gh[j] = (_Float16)val;
                }
            }
            f2 kl = __builtin_bit_cast(f2, kh);
            f2 gl = __builtin_bit_cast(f2, gh);
            f4 o = (f4){kl.x, kl.y, gl.x, gl.y};
            Kf[tileg*64 + r + 16*g] = o;
        }
    } else {
        #pragma unroll
        for (int d = 0; d < DD; ++d) Qp[pos*8 + d] = y[d] * LOG2E;
        Qp[pos*8 + 6] = 0.f;
        Qp[pos*8 + 7] = 0.f;
    }
}

// ---------------- Kernel B: MFMA attention ----------------
// Block = (query group of 64) x (voxel chunk of 1152). 4 waves, one 16-query
// fragment each; all waves stream the same 72 K/G tile lines (L1 reuse).
// Per tile: MFMA1 logits -> exp2 -> pack -> MFMA2 accumulate (ct,ch,cw,sum).
__global__ __launch_bounds__(256) void attn_kernel(
    const f4* __restrict__ Kf, const float* __restrict__ Qp,
    float* __restrict__ Pc)
{
    int tid  = threadIdx.x;
    int wv   = tid >> 6;
    int lane = tid & 63;
    int g = lane >> 4, r = lane & 15;
    int qg = blockIdx.x >> 5;          // / NCH
    int ch = blockIdx.x & (NCH-1);
    int qbase = qg*QG + wv*16;

    // B-frag of MFMA1: lane holds Q[query=r][features g*4+j] (zeros for g>=2)
    h4 qf = (h4){0,0,0,0};
    if (g < 2) {
        f4 qv = *(const f4*)(Qp + (qbase + r)*8 + g*4);
        qf = (h4){ (_Float16)qv.x, (_Float16)qv.y, (_Float16)qv.z, (_Float16)qv.w };
    }

    f4 z   = (f4){0,0,0,0};
    f4 out = (f4){0,0,0,0};
    const f4* kp = Kf + (ch*TPC)*64 + lane;
    #pragma unroll 4
    for (int it = 0; it < TPC; ++it) {
        f4 v = kp[it*64];
        h4 ka = __builtin_bit_cast(h4, (f2){v.x, v.y});
        h4 ga = __builtin_bit_cast(h4, (f2){v.z, v.w});
        // logits: D[voxel][query]; this lane gets query=r, voxels g*4+reg
        f4 s = __builtin_amdgcn_mfma_f32_16x16x16f16(ka, qf, z, 0, 0, 0);
        float p0 = __builtin_amdgcn_exp2f(s.x);
        float p1 = __builtin_amdgcn_exp2f(s.y);
        float p2 = __builtin_amdgcn_exp2f(s.z);
        float p3 = __builtin_amdgcn_exp2f(s.w);
        h2 pl = __builtin_bit_cast(h2, __builtin_amdgcn_cvt_pkrtz(p0, p1));
        h2 ph = __builtin_bit_cast(h2, __builtin_amdgcn_cvt_pkrtz(p2, p3));
        h4 pf = (h4){pl.x, pl.y, ph.x, ph.y};   // A-frag of MFMA2: row=query=r, k=voxel g*4+j
        out = __builtin_amdgcn_mfma_f32_16x16x16f16(pf, ga, out, 0, 0, 0);
    }
    // Out: lane holds queries g*4+reg at column c=r (c<4: ct,ch,cw,sum)
    if (r < 4) {
        #pragma unroll
        for (int j = 0; j < 4; ++j) {
            int q = qbase + g*4 + j;
            Pc[(ch*SS + q)*4 + r] = out[j];
        }
    }
}

// ---------------- Kernel C: merge chunks, finalize flow ----------------
__global__ __launch_bounds__(256) void final_kernel(
    const f4* __restrict__ Pc, float* __restrict__ out)
{
    int q = blockIdx.x * 256 + threadIdx.x;
    if (q >= SS) return;
    f4 a = (f4){0,0,0,0};
    #pragma unroll
    for (int c = 0; c < NCH; ++c) a += Pc[c*SS + q];
    float inv = 1.f / a.w;
    int h = q / WW;
    int w = q - h*WW;
    out[q]        = a.x * inv;                        // t-channel (slice t grid = 0)
    out[SS + q]   = a.y * inv - ((float)h - 23.5f);   // h-channel
    out[2*SS + q] = a.z * inv - ((float)w - 23.5f);   // w-channel
}

extern "C" void kernel_launch(void* const* d_in, const int* in_sizes, int n_in,
                              void* d_out, int out_size, void* d_ws, size_t ws_size,
                              hipStream_t stream)
{
    const float* vol  = (const float*)d_in[0];
    const float* slc  = (const float*)d_in[1];
    const float* w2d  = (const float*)d_in[2];
    const float* b2d  = (const float*)d_in[3];
    const float* g2d  = (const float*)d_in[4];
    const float* be2d = (const float*)d_in[5];
    const float* w3d  = (const float*)d_in[6];
    const float* b3d  = (const float*)d_in[7];
    const float* g3d  = (const float*)d_in[8];
    const float* be3d = (const float*)d_in[9];
    float* out = (float*)d_out;

    // workspace: Kf (2304 tiles * 64 lanes * 16B = 2.36MB) | Qp (73.7KB) | Pc (1.18MB)
    f4*    Kf = (f4*)d_ws;
    float* Qp = (float*)(Kf + NT*64);
    f4*    Pc = (f4*)(Qp + SS*8);

    proj_kernel<<<(VS + SS)/256, 256, 0, stream>>>(vol, slc, w2d, b2d, g2d, be2d,
                                                   w3d, b3d, g3d, be3d, Kf, Qp);
    attn_kernel<<<NQG*NCH, 256, 0, stream>>>(Kf, Qp, (float*)Pc);
    final_kernel<<<(SS + 255)/256, 256, 0, stream>>>(Pc, out);
}